// Round 19
// baseline (159.428 us; speedup 1.0000x reference)
//
#include <hip/hip_runtime.h>
#include <math.h>

// b=4,n=2048 -> 8192 rows; d=1024; h=8; e=16; cs=2048. Output int32 [8192,8].
// argmax_c q.cbn_c == argmax_c ((x.W - mu*colsum(W)) . cbn_c). Codebook fp64-
// normalized. bf16 3-split MFMA path (verified R7..R17): v = h+m+l (8+8+8
// mantissa bits, fp32 exponent range); v_p*v_c ~= hh + hm+mh + hl+mm+lh via 3
// quad-packed K=32 bf16 MFMAs. Frag-major B layouts (R9/R10).
//
// R19: R17 structure (512 thr — proven launch domain; R18's 1024thr/72KB
// config never launched) with LDS cut 67->48.4 KB so 3 blocks/CU fit
// (6 waves/SIMD, +50% latency hiding): x staged in 2 chunks of 512 d
// (pitch 548 = 4 mod 32, conflict-free), reduce slots reuse the x buffer,
// tS separate.

typedef short bf16x8 __attribute__((ext_vector_type(8)));
typedef float f32x4 __attribute__((ext_vector_type(4)));

__device__ __forceinline__ void stage16(const float* g, float* lds_base) {
  __builtin_amdgcn_global_load_lds(
      (const __attribute__((address_space(1))) void*)g,
      (__attribute__((address_space(3))) void*)lds_base, 16, 0, 0);
}

__device__ __forceinline__ unsigned short f2bf(float f) {
  unsigned u = __builtin_bit_cast(unsigned, f);
  unsigned r = (u + 0x7FFFu + ((u >> 16) & 1u)) >> 16;   // RNE
  return (unsigned short)r;
}
__device__ __forceinline__ float bf2f(unsigned short b) {
  return __builtin_bit_cast(float, (unsigned)b << 16);
}
__device__ __forceinline__ void split3(float v, unsigned short& h,
                                       unsigned short& m, unsigned short& l) {
  h = f2bf(v);
  float r = v - bf2f(h);
  m = f2bf(r);
  float r2 = r - bf2f(m);
  l = f2bf(r2);
}

// ---------------- K1: fused prep: cbnorm | colsum | wsplit (verified) -------
__global__ __launch_bounds__(256) void k_prep(const float* __restrict__ cb,
                                              const float* __restrict__ W,
                                              unsigned short* __restrict__ cfrag,
                                              float* __restrict__ csum,
                                              unsigned short* __restrict__ wfrag) {
  __shared__ float red[16][17];
  const int bid = blockIdx.x;
  const int t = threadIdx.x;
  if (bid < 64) {            // ---- cbnorm (fp64 normalize + bf16 3-split)
    int v = bid * 256 + t;
    int h = v >> 11, c = v & 2047, tl = c >> 4, n = c & 15;
    const float4* p = (const float4*)(cb + (size_t)v * 16);
    float4 q0 = p[0], q1 = p[1], q2 = p[2], q3 = p[3];
    float f[16] = {q0.x,q0.y,q0.z,q0.w, q1.x,q1.y,q1.z,q1.w,
                   q2.x,q2.y,q2.z,q2.w, q3.x,q3.y,q3.z,q3.w};
    double s = 0.0;
#pragma unroll
    for (int i = 0; i < 16; ++i) s += (double)f[i] * (double)f[i];
    double inv = 1.0 / sqrt(s + 1e-12);
    __attribute__((aligned(16))) unsigned short vp[3][16];
#pragma unroll
    for (int i = 0; i < 16; ++i)
      split3((float)((double)f[i] * inv), vp[0][i], vp[1][i], vp[2][i]);
#pragma unroll
    for (int pp = 0; pp < 3; ++pp) {
      size_t base = ((((size_t)h * 128 + tl) * 3 + pp) * 16 + n) * 16;
      ((bf16x8*)(cfrag + base))[0] = ((bf16x8*)vp[pp])[0];
      ((bf16x8*)(cfrag + base))[1] = ((bf16x8*)vp[pp])[1];
    }
  } else if (bid < 72) {     // ---- colsum
    int h = bid - 64;
    int e = t & 15, part = t >> 4;
    const float* base = W + h * 16384 + e;
    float s = 0.f;
    int d0 = part * 64;
    for (int i = 0; i < 64; ++i) s += base[(d0 + i) * 16];
    red[e][part] = s;
    __syncthreads();
    if (t < 16) {
      float tt = 0.f;
#pragma unroll
      for (int p = 0; p < 16; ++p) tt += red[t][p];
      csum[h * 16 + t] = tt;
    }
  } else {                   // ---- wsplit
    int id = (bid - 72) * 256 + t;
    int o = id & 1, n = (id >> 1) & 15, c = (id >> 5) & 7, dg = id >> 8;
    __attribute__((aligned(16))) unsigned short vp[3][8];
#pragma unroll
    for (int j = 0; j < 8; ++j) {
      float v = W[c * 16384 + (dg * 16 + o * 8 + j) * 16 + n];
      split3(v, vp[0][j], vp[1][j], vp[2][j]);
    }
#pragma unroll
    for (int pp = 0; pp < 3; ++pp) {
      size_t base = ((((size_t)dg * 8 + c) * 3 + pp) * 16 + n) * 16 + o * 8;
      *(bf16x8*)(wfrag + base) = *(bf16x8*)vp[pp];
    }
  }
}

// ---------------- K2: fused proj + argmax, 48.4 KB LDS (3 blocks/CU) --------
// Grid 512 x 512 threads. Block = 16 rows. Phase 1: x staged in 2 chunks of
// 512 d (pitch 548); wave w = local d-groups [4w,4w+4) per chunk (8 total);
// wave-pair reduce into xbuf-resident slots; epilogue -> tS. Phase 2: wave w
// = head w, all 2048 codes; direct out write (R17 verbatim).
__global__ __launch_bounds__(512) void k_main(
    const float* __restrict__ x, const unsigned short* __restrict__ wfrag,
    const unsigned short* __restrict__ cfrag, const float* __restrict__ csum,
    int* __restrict__ out) {
  __shared__ __align__(16) float xbuf[16 * 548];     // 35072 B (x, then sAcc)
  __shared__ __align__(16) unsigned short tS[6144];  // 12288 B [p][row][head][e]
  __shared__ float sPs[8][2][16];
  __shared__ float sMu[16];
  const int t = threadIdx.x;
  const int lane = t & 63, w = t >> 6;        // wave 0..7
  const int r0 = blockIdx.x * 16;
  const int q = lane >> 4, n16 = lane & 15, oct = q & 1;
  const bool qlt2 = (q < 2);
  const int p1 = qlt2 ? 0 : 1, p2 = qlt2 ? 1 : 0, p3 = qlt2 ? 2 : 0;
  const int ehalf = oct * 8;

  // ---------- Phase 1: projection, K in 2 chunks of 512 ----------
  f32x4 acc[8];
#pragma unroll
  for (int h = 0; h < 8; ++h) acc[h] = (f32x4){0.f, 0.f, 0.f, 0.f};
  float ps = 0.f;

  for (int c = 0; c < 2; ++c) {
    __syncthreads();           // protect previous chunk's reads
    // stage chunk: wave w stages rows {2w, 2w+1}, 2 dense 1KB insts per row
#pragma unroll
    for (int rr = 0; rr < 2; ++rr)
#pragma unroll
      for (int j = 0; j < 2; ++j)
        stage16(x + (size_t)(r0 + 2 * w + rr) * 1024 + c * 512 + j * 256 + lane * 4,
                xbuf + (2 * w + rr) * 548 + j * 256);
    __syncthreads();

#pragma unroll
    for (int dg2 = 0; dg2 < 4; ++dg2) {
      const int dgl = w * 4 + dg2;             // local d-group 0..31
      const int dg = c * 32 + dgl;             // GLOBAL d-group (R9 lesson)
      const int dql = dgl * 16 + oct * 8;      // local xbuf offset
      float4 xa = *(const float4*)(xbuf + n16 * 548 + dql);
      float4 xb = *(const float4*)(xbuf + n16 * 548 + dql + 4);
      float xf[8] = {xa.x, xa.y, xa.z, xa.w, xb.x, xb.y, xb.z, xb.w};
      ps += ((xf[0] + xf[1]) + (xf[2] + xf[3])) +
            ((xf[4] + xf[5]) + (xf[6] + xf[7]));
      __attribute__((aligned(16))) unsigned short s1[8], s3[8];
#pragma unroll
      for (int j = 0; j < 8; ++j) {
        unsigned short hh, mm, ll;
        split3(xf[j], hh, mm, ll);
        s1[j] = qlt2 ? hh : mm;
        s3[j] = qlt2 ? hh : ll;
      }
      bf16x8 a1 = *(bf16x8*)s1;
      bf16x8 a3 = *(bf16x8*)s3;
#pragma unroll
      for (int hh = 0; hh < 8; ++hh) {
        size_t b0 = (((size_t)(dg * 8 + hh) * 3) * 16 + n16) * 16 + oct * 8;
        bf16x8 b1 = *(const bf16x8*)(wfrag + b0 + p1 * 256);
        bf16x8 b2 = *(const bf16x8*)(wfrag + b0 + p2 * 256);
        bf16x8 b3 = *(const bf16x8*)(wfrag + b0 + p3 * 256);
        acc[hh] = __builtin_amdgcn_mfma_f32_16x16x32_bf16(a1, b1, acc[hh], 0, 0, 0);
        acc[hh] = __builtin_amdgcn_mfma_f32_16x16x32_bf16(a1, b2, acc[hh], 0, 0, 0);
        acc[hh] = __builtin_amdgcn_mfma_f32_16x16x32_bf16(a3, b3, acc[hh], 0, 0, 0);
      }
    }
  }

  if (q < 2) sPs[w][q][n16] = ps;
  __syncthreads();             // x reads done; xbuf reused as reduce buffer
  float* sAcc = xbuf;          // 4 slots x 64 x 33 = 8448 floats (<= 8768)

  if (w >= 4) {
#pragma unroll
    for (int hh = 0; hh < 8; ++hh)
#pragma unroll
      for (int r = 0; r < 4; ++r)
        sAcc[((w - 4) * 64 + lane) * 33 + hh * 4 + r] = acc[hh][r];
  }
  __syncthreads();
  if (w < 4) {
#pragma unroll
    for (int hh = 0; hh < 8; ++hh)
#pragma unroll
      for (int r = 0; r < 4; ++r)
        sAcc[(w * 64 + lane) * 33 + hh * 4 + r] =
            acc[hh][r] + sAcc[(w * 64 + lane) * 33 + hh * 4 + r];
  }
  if (t < 16) {
    float s = 0.f;
#pragma unroll
    for (int w2 = 0; w2 < 8; ++w2) s += sPs[w2][0][t] + sPs[w2][1][t];
    sMu[t] = s * (1.0f / 1024.0f);
  }
  __syncthreads();

  {  // epilogue: thread (head = t>>6, l = t&63) -> 4 cells -> tS (LDS)
    const int l = t & 63, head = t >> 6;
    const int lq = l >> 4, ln = l & 15;
    const float cs = csum[head * 16 + ln];
#pragma unroll
    for (int r = 0; r < 4; ++r) {
      const int f = head * 4 + r;
      float v = ((sAcc[(0 * 64 + l) * 33 + f] + sAcc[(1 * 64 + l) * 33 + f]) +
                 (sAcc[(2 * 64 + l) * 33 + f] + sAcc[(3 * 64 + l) * 33 + f]));
      const int row16 = lq * 4 + r;
      float tv = v - sMu[row16] * cs;
      unsigned short vh, vm, vl;
      split3(tv, vh, vm, vl);
      const int base = (row16 * 8 + head) * 16 + ln;
      tS[base] = vh;                 // p=0
      tS[2048 + base] = vm;          // p=1
      tS[4096 + base] = vl;          // p=2
    }
  }
  __syncthreads();

  // ---------- Phase 2: argmax, wave w = head w, all 2048 codes ----------
  {
    const int h = w;
    const int pa3 = qlt2 ? 0 : 2;    // A3 = [h|l] (A-side part select)
    bf16x8 a1 = *(const bf16x8*)(tS + (p1 * 2048 + (n16 * 8 + h) * 16) + ehalf);
    bf16x8 a3 = *(const bf16x8*)(tS + (pa3 * 2048 + (n16 * 8 + h) * 16) + ehalf);

    float best[4];
    int   bidx[4];
#pragma unroll
    for (int r = 0; r < 4; ++r) { best[r] = -3.402823466e38f; bidx[r] = 0; }

#pragma unroll 4
    for (int tile = 0; tile < 128; ++tile) {
      size_t b0 = (((size_t)(h * 128 + tile) * 3) * 16 + n16) * 16 + ehalf;
      bf16x8 b1 = *(const bf16x8*)(cfrag + b0 + p1 * 256);
      bf16x8 b2 = *(const bf16x8*)(cfrag + b0 + p2 * 256);
      bf16x8 b3 = *(const bf16x8*)(cfrag + b0 + p3 * 256);
      f32x4 a = {0.f, 0.f, 0.f, 0.f};
      a = __builtin_amdgcn_mfma_f32_16x16x32_bf16(a1, b1, a, 0, 0, 0);
      a = __builtin_amdgcn_mfma_f32_16x16x32_bf16(a1, b2, a, 0, 0, 0);
      a = __builtin_amdgcn_mfma_f32_16x16x32_bf16(a3, b3, a, 0, 0, 0);
      const int code = tile * 16 + n16;
#pragma unroll
      for (int r = 0; r < 4; ++r)
        if (a[r] > best[r]) { best[r] = a[r]; bidx[r] = code; }
    }

#pragma unroll
    for (int off = 8; off >= 1; off >>= 1) {
#pragma unroll
      for (int r = 0; r < 4; ++r) {
        float ov = __shfl_xor(best[r], off, 16);
        int   oi = __shfl_xor(bidx[r], off, 16);
        if (ov > best[r] || (ov == best[r] && oi < bidx[r])) {
          best[r] = ov; bidx[r] = oi;
        }
      }
    }
    if (n16 == 0) {
#pragma unroll
      for (int r = 0; r < 4; ++r)
        out[(size_t)(r0 + q * 4 + r) * 8 + h] = bidx[r];
    }
  }
}

extern "C" void kernel_launch(void* const* d_in, const int* in_sizes, int n_in,
                              void* d_out, int out_size, void* d_ws, size_t ws_size,
                              hipStream_t stream) {
  (void)in_sizes; (void)n_in; (void)out_size; (void)ws_size;
  const float* x  = (const float*)d_in[0];   // [4,2048,1024]
  const float* rp = (const float*)d_in[1];   // [8,1024,16]
  const float* cb = (const float*)d_in[2];   // [8,2048,16]
  int* out = (int*)d_out;                    // [8192,8] int32

  float* ws = (float*)d_ws;
  float*          csum  = ws;                             // 128
  unsigned short* wfrag = (unsigned short*)(ws + 128);    // 393216 sh
  unsigned short* cfrag = (unsigned short*)(ws + 196736); // 786432 sh (~3.3MB)

  hipLaunchKernelGGL(k_prep, dim3(136), dim3(256), 0, stream,
                     cb, rp, cfrag, csum, wfrag);
  hipLaunchKernelGGL(k_main, dim3(512), dim3(512), 0, stream,
                     x, wfrag, cfrag, csum, out);
}